// Round 1
// baseline (5151.734 us; speedup 1.0000x reference)
//
#include <hip/hip_runtime.h>
#include <math.h>

// CIN (xDeepFM) fused kernels — fp32 baseline.
// B=512, F=32, D=64, O=128 per layer; K0=1024, K1=K2=4096.
// Layer: y[b,o,d] = bias[o] + sum_{f,h} W[o, f*H+h] * x[b,f,d] * hin[b,h,d]
// outs[b, col_off+o] = sum_d y[b,o,d]
// final: out[b] = sigmoid( sum_j relu(outs[b,j]) * Wout[j] + bout )

#define B_SZ 512
#define F_SZ 32
#define D_SZ 64
#define O_SZ 128

template <int H>
__global__ __launch_bounds__(256, 2) void cin_layer_kernel(
    const float* __restrict__ x,     // (B, 32, 64)
    const float* __restrict__ hin,   // (B, H, 64)
    const float* __restrict__ W,     // (128, 32*H)
    const float* __restrict__ bias,  // (128)
    float* __restrict__ yout,        // (B, 128, 64)
    float* __restrict__ outs,        // (B, 384)
    int col_off)
{
    constexpr int K = F_SZ * H;
    const int b    = blockIdx.x;
    const int lane = threadIdx.x & 63;
    const int wid  = threadIdx.x >> 6;   // wave id 0..3
    const int d    = lane;

    __shared__ float sh_h[H * D_SZ];     // 32 KB for H=128
    __shared__ float sh_x[F_SZ * D_SZ];  // 8 KB

    const float* hb = hin + (size_t)b * H * D_SZ;
    const float* xb = x   + (size_t)b * F_SZ * D_SZ;
    for (int i = threadIdx.x; i < H * D_SZ; i += 256) sh_h[i] = hb[i];
    for (int i = threadIdx.x; i < F_SZ * D_SZ; i += 256) sh_x[i] = xb[i];
    __syncthreads();

    const int o0 = wid * 32;             // this wave's 32 output channels
    float acc[32];
#pragma unroll
    for (int i = 0; i < 32; ++i) acc[i] = 0.f;

    for (int f = 0; f < F_SZ; ++f) {
        const float xv = sh_x[f * D_SZ + d];
        for (int h = 0; h < H; h += 4) {
            const float z0 = xv * sh_h[(h + 0) * D_SZ + d];
            const float z1 = xv * sh_h[(h + 1) * D_SZ + d];
            const float z2 = xv * sh_h[(h + 2) * D_SZ + d];
            const float z3 = xv * sh_h[(h + 3) * D_SZ + d];
            const float* wp = W + (size_t)o0 * K + (f * H + h);
#pragma unroll
            for (int i = 0; i < 32; ++i) {
                const float4 wq = *reinterpret_cast<const float4*>(wp + (size_t)i * K);
                acc[i] = fmaf(wq.x, z0, acc[i]);
                acc[i] = fmaf(wq.y, z1, acc[i]);
                acc[i] = fmaf(wq.z, z2, acc[i]);
                acc[i] = fmaf(wq.w, z3, acc[i]);
            }
        }
    }

    float* yb = yout + (size_t)b * O_SZ * D_SZ;
#pragma unroll
    for (int i = 0; i < 32; ++i) {
        const float yv = acc[i] + bias[o0 + i];
        yb[(o0 + i) * D_SZ + d] = yv;
        // wave-reduce over the 64 d-lanes for outs
        float s = yv;
#pragma unroll
        for (int m = 32; m; m >>= 1) s += __shfl_xor(s, m, 64);
        if (lane == 0) outs[(size_t)b * 384 + col_off + o0 + i] = s;
    }
}

__global__ __launch_bounds__(64) void cin_final_kernel(
    const float* __restrict__ outs,   // (B, 384)
    const float* __restrict__ Wout,   // (384, 1)
    const float* __restrict__ bout,   // (1)
    float* __restrict__ out)          // (B, 1)
{
    const int b    = blockIdx.x;
    const int lane = threadIdx.x;
    float p = 0.f;
    for (int j = lane; j < 384; j += 64) {
        float v = outs[(size_t)b * 384 + j];
        v = v > 0.f ? v : 0.f;
        p = fmaf(v, Wout[j], p);
    }
#pragma unroll
    for (int m = 32; m; m >>= 1) p += __shfl_xor(p, m, 64);
    if (lane == 0) {
        const float t = p + bout[0];
        out[b] = 1.f / (1.f + expf(-t));
    }
}

extern "C" void kernel_launch(void* const* d_in, const int* in_sizes, int n_in,
                              void* d_out, int out_size, void* d_ws, size_t ws_size,
                              hipStream_t stream)
{
    const float* x    = (const float*)d_in[0];
    const float* W0   = (const float*)d_in[1];
    const float* b0   = (const float*)d_in[2];
    const float* W1   = (const float*)d_in[3];
    const float* b1   = (const float*)d_in[4];
    const float* W2   = (const float*)d_in[5];
    const float* b2   = (const float*)d_in[6];
    const float* Wout = (const float*)d_in[7];
    const float* bout = (const float*)d_in[8];
    float* out = (float*)d_out;

    char* ws = (char*)d_ws;
    const size_t hbytes = (size_t)B_SZ * O_SZ * D_SZ * sizeof(float);  // 16 MB
    float* h1   = (float*)(ws);
    float* h2   = (float*)(ws + hbytes);
    float* outs = (float*)(ws + 2 * hbytes);                           // 768 KB

    cin_layer_kernel<32> <<<B_SZ, 256, 0, stream>>>(x, x,  W0, b0, h1, outs, 0);
    cin_layer_kernel<128><<<B_SZ, 256, 0, stream>>>(x, h1, W1, b1, h2, outs, 128);
    cin_layer_kernel<128><<<B_SZ, 256, 0, stream>>>(x, h2, W2, b2, h1, outs, 256);
    cin_final_kernel<<<B_SZ, 64, 0, stream>>>(outs, Wout, bout, out);
}

// Round 3
// 218.655 us; speedup vs baseline: 23.5611x; 23.5611x over previous
//
#include <hip/hip_runtime.h>
#include <math.h>

// CIN (xDeepFM) — split-bf16 MFMA version (fp32-accurate).
// y[b,o,d] = bias[o] + sum_f x[b,f,d] * ( sum_h W[o,f*H+h] * h_in[b,h,d] )
// Inner sum: 16x16x32 bf16 MFMA with W,h each split hi+lo bf16:
//   W*h ~= Whi*hhi + Whi*hlo + Wlo*hhi   (lo*lo dropped, ~2^-18 rel)
// B=512, F=32, D=64, O=128; H0=32 (h=x), H1=H2=128.

typedef __attribute__((ext_vector_type(8))) short bf16x8;
typedef __attribute__((ext_vector_type(4))) float f32x4;
typedef __attribute__((ext_vector_type(4))) unsigned short u16x4;

#define HT_LO 4194304   // shorts: 512*64*128 (offset of lo plane)

__device__ __forceinline__ unsigned short f2bf(float f) {
  unsigned int u = __float_as_uint(f);
  u = (u + 0x7fffu + ((u >> 16) & 1u)) >> 16;   // RNE
  return (unsigned short)u;
}
__device__ __forceinline__ float bf2f(unsigned short h) {
  return __uint_as_float((unsigned int)h << 16);
}

__device__ __forceinline__ void gll16(const void* g, void* l) {
  __builtin_amdgcn_global_load_lds(
      (const __attribute__((address_space(1))) unsigned int*)g,
      (__attribute__((address_space(3))) unsigned int*)l, 16, 0, 0);
}

// ---- pre-pass: repack W (fp32, row-major 128xK) into split-bf16 fragment-linear image.
// f-chunk layout (bytes): [s in {hi,lo}][ksl][idx=mt*64+lane] * 16
// element: W[o = mt*16+(l&15)][c = f*H + pass*64 + ksl*32 + (l>>4)*8 + j], j=0..7
__global__ void repack_w_kernel(const float* __restrict__ W, unsigned short* __restrict__ dst,
                                int H, int NP, int KSP, int nchunks)
{
  const int t = blockIdx.x * 256 + threadIdx.x;
  if (t >= nchunks) return;
  const int K = 32 * H;
  const int cpf = NP * KSP * 512;
  const int f = t / cpf;
  int r = t % cpf;
  const int pass = r / (KSP * 512); r %= (KSP * 512);
  const int ksl = r / 512;
  const int idx = r % 512;
  const int mt = idx >> 6, l = idx & 63;
  const int o = mt * 16 + (l & 15);
  const int c = f * H + pass * 64 + ksl * 32 + (l >> 4) * 8;
  const float* s = W + (size_t)o * K + c;
  u16x4 h0, h1, l0, l1;
#pragma unroll
  for (int j = 0; j < 4; ++j) {
    float v = s[j];
    unsigned short hb = f2bf(v);
    h0[j] = hb; l0[j] = f2bf(v - bf2f(hb));
    v = s[4 + j];
    hb = f2bf(v);
    h1[j] = hb; l1[j] = f2bf(v - bf2f(hb));
  }
  // hi at s=0 plane, lo at s=1 plane within the f-chunk
  const size_t chunk_hi = ((size_t)((f * NP + pass) * 2 + 0) * KSP + ksl) * 512 + idx;
  const size_t chunk_lo = ((size_t)((f * NP + pass) * 2 + 1) * KSP + ksl) * 512 + idx;
  *(u16x4*)(dst + chunk_hi * 8)     = h0;
  *(u16x4*)(dst + chunk_hi * 8 + 4) = h1;
  *(u16x4*)(dst + chunk_lo * 8)     = l0;
  *(u16x4*)(dst + chunk_lo * 8 + 4) = l1;
}

// ---- main layer kernel ----
// grid 512 blocks x 512 threads; block b. Wave w owns o in [16w, 16w+16).
// LDS: [0, 2*CHUNK) = W chunk double buffer; [2*CHUNK, +8KB) = raw x[b] (32x64 fp32).
template<int H, int NPASS, int KSP, bool FIRST, bool STORE_H>
__global__ __launch_bounds__(512) void cin_mfma_layer(
    const unsigned short* __restrict__ Wimg,
    const float* __restrict__ x,               // (B,32,64) fp32
    const unsigned short* __restrict__ hTin,   // hi plane; lo at +HT_LO  (null if FIRST)
    const float* __restrict__ bias,
    unsigned short* __restrict__ hTout,        // hi plane; lo at +HT_LO
    float* __restrict__ outs, int col_off)
{
  constexpr int CHUNK = 2 * KSP * 8192;        // bytes per f-chunk (hi+lo)
  constexpr int SR = 2 * KSP;                  // staging rounds per chunk
  constexpr int XOFF = 2 * CHUNK;
  __shared__ char lds[2 * CHUNK + 8192];
  const int tid = threadIdx.x;
  const int w = tid >> 6, l = tid & 63, g = l >> 4, li = l & 15;
  const int b = blockIdx.x;
  const float* lx = (const float*)(lds + XOFF);

  // stage raw x[b] (8 KB, lane-linear)
  gll16(x + (size_t)b * 2048 + tid * 4, lds + XOFF + (w * 64) * 16);

  f32x4 Y[4];
#pragma unroll
  for (int nt = 0; nt < 4; ++nt) Y[nt] = (f32x4){0.f, 0.f, 0.f, 0.f};
  const f32x4 zero4 = (f32x4){0.f, 0.f, 0.f, 0.f};

  bf16x8 Bh[KSP][4], Bl[KSP][4];
  int cur = 0;

  for (int pass = 0; pass < NPASS; ++pass) {
    if constexpr (!FIRST) {
      // B-fragments for this pass (reused across all 32 f)
#pragma unroll
      for (int ks = 0; ks < KSP; ++ks)
#pragma unroll
        for (int nt = 0; nt < 4; ++nt) {
          const int d = nt * 16 + li;
          const size_t off = (size_t)b * 8192 + d * 128 + pass * 64 + ks * 32 + g * 8;
          Bh[ks][nt] = *(const bf16x8*)(hTin + off);
          Bl[ks][nt] = *(const bf16x8*)(hTin + HT_LO + off);
        }
    }
    // stage W chunk (f=0, pass) into buf cur
    {
      const char* src = (const char*)Wimg + (size_t)(0 * NPASS + pass) * CHUNK;
#pragma unroll
      for (int r = 0; r < SR; ++r)
        gll16(src + (size_t)(r * 512 + tid) * 16,
              lds + cur * CHUNK + (r * 512 + w * 64) * 16);
    }
    asm volatile("s_waitcnt vmcnt(0)" ::: "memory");
    __builtin_amdgcn_s_barrier();

    if constexpr (FIRST) {
      // build split B-fragments from raw x in LDS (pass 0 only; NPASS==1)
#pragma unroll
      for (int nt = 0; nt < 4; ++nt) {
        union { bf16x8 v; unsigned short u[8]; } th, tl;
#pragma unroll
        for (int j = 0; j < 8; ++j) {
          const float xv = lx[(g * 8 + j) * 64 + nt * 16 + li];
          const unsigned short hb = f2bf(xv);
          th.u[j] = hb;
          tl.u[j] = f2bf(xv - bf2f(hb));
        }
        Bh[0][nt] = th.v;
        Bl[0][nt] = tl.v;
      }
    }

    for (int f = 0; f < 32; ++f) {
      if (f < 31) {
        const char* src = (const char*)Wimg + (size_t)((f + 1) * NPASS + pass) * CHUNK;
#pragma unroll
        for (int r = 0; r < SR; ++r)
          gll16(src + (size_t)(r * 512 + tid) * 16,
                lds + (cur ^ 1) * CHUNK + (r * 512 + w * 64) * 16);
        asm volatile("s_waitcnt vmcnt(%0)" :: "i"(SR) : "memory");
      } else {
        asm volatile("s_waitcnt vmcnt(0)" ::: "memory");
      }
      __builtin_amdgcn_s_barrier();

      f32x4 G[4];
#pragma unroll
      for (int ks = 0; ks < KSP; ++ks) {
        const bf16x8 Ah = *(const bf16x8*)(lds + cur * CHUNK + (((0 * KSP + ks) * 8 + w) * 64 + l) * 16);
        const bf16x8 Al = *(const bf16x8*)(lds + cur * CHUNK + (((1 * KSP + ks) * 8 + w) * 64 + l) * 16);
#pragma unroll
        for (int nt = 0; nt < 4; ++nt) {
          G[nt] = __builtin_amdgcn_mfma_f32_16x16x32_bf16(Ah, Bh[ks][nt],
                      (ks == 0) ? zero4 : G[nt], 0, 0, 0);
          G[nt] = __builtin_amdgcn_mfma_f32_16x16x32_bf16(Ah, Bl[ks][nt], G[nt], 0, 0, 0);
          G[nt] = __builtin_amdgcn_mfma_f32_16x16x32_bf16(Al, Bh[ks][nt], G[nt], 0, 0, 0);
        }
      }
#pragma unroll
      for (int nt = 0; nt < 4; ++nt) {
        const float sc = lx[f * 64 + nt * 16 + li];   // fp32 x-scale (broadcast read)
        Y[nt] += G[nt] * sc;
      }
      cur ^= 1;
    }
  }

  // ---- epilogue: bias, split-hT store, outs row-sums ----
  const f32x4 bv = *(const f32x4*)(bias + w * 16 + g * 4);
#pragma unroll
  for (int nt = 0; nt < 4; ++nt) Y[nt] += bv;

  if constexpr (STORE_H) {
#pragma unroll
    for (int nt = 0; nt < 4; ++nt) {
      const int d = nt * 16 + li;
      u16x4 ph, pl;
#pragma unroll
      for (int j = 0; j < 4; ++j) {
        const unsigned short hb = f2bf(Y[nt][j]);
        ph[j] = hb;
        pl[j] = f2bf(Y[nt][j] - bf2f(hb));
      }
      const size_t off = (size_t)b * 8192 + d * 128 + w * 16 + g * 4;
      *(u16x4*)(hTout + off)         = ph;
      *(u16x4*)(hTout + HT_LO + off) = pl;
    }
  }

  {
    f32x4 s = Y[0] + Y[1] + Y[2] + Y[3];
#pragma unroll
    for (int m = 1; m < 16; m <<= 1) {
      s.x += __shfl_xor(s.x, m, 16);
      s.y += __shfl_xor(s.y, m, 16);
      s.z += __shfl_xor(s.z, m, 16);
      s.w += __shfl_xor(s.w, m, 16);
    }
    if (li == 0)
      *(f32x4*)(outs + (size_t)b * 384 + col_off + w * 16 + g * 4) = s;
  }
}

// ---- final: out[b] = sigmoid( relu(outs[b,:]) . Wout + bout ) ----
__global__ __launch_bounds__(64) void cin_final_kernel(
    const float* __restrict__ outs, const float* __restrict__ Wout,
    const float* __restrict__ bout, float* __restrict__ out)
{
  const int b = blockIdx.x;
  const int lane = threadIdx.x;
  float p = 0.f;
  for (int j = lane; j < 384; j += 64) {
    float v = outs[(size_t)b * 384 + j];
    v = v > 0.f ? v : 0.f;
    p = fmaf(v, Wout[j], p);
  }
#pragma unroll
  for (int m = 32; m; m >>= 1) p += __shfl_xor(p, m, 64);
  if (lane == 0) {
    const float t = p + bout[0];
    out[b] = 1.f / (1.f + expf(-t));
  }
}

extern "C" void kernel_launch(void* const* d_in, const int* in_sizes, int n_in,
                              void* d_out, int out_size, void* d_ws, size_t ws_size,
                              hipStream_t stream)
{
  const float* x    = (const float*)d_in[0];
  const float* W0   = (const float*)d_in[1];
  const float* b0   = (const float*)d_in[2];
  const float* W1   = (const float*)d_in[3];
  const float* b1   = (const float*)d_in[4];
  const float* W2   = (const float*)d_in[5];
  const float* b2   = (const float*)d_in[6];
  const float* Wout = (const float*)d_in[7];
  const float* bout = (const float*)d_in[8];
  float* out = (float*)d_out;

  char* ws = (char*)d_ws;
  unsigned short* hT1  = (unsigned short*)ws;                    // 16 MB (hi+lo)
  unsigned short* hT2  = (unsigned short*)(ws + (16 << 20));     // 16 MB
  float*          outs = (float*)        (ws + (32 << 20));      // 768 KB
  unsigned short* Wi0  = (unsigned short*)(ws + (33 << 20));               // 512 KB
  unsigned short* Wi1  = (unsigned short*)(ws + (33 << 20) + (1 << 19));   // 2 MB
  unsigned short* Wi2  = (unsigned short*)(ws + (33 << 20) + (1 << 19) + (2 << 20)); // 2 MB

  repack_w_kernel<<<64,  256, 0, stream>>>(W0, Wi0, 32,  1, 1, 16384);
  repack_w_kernel<<<256, 256, 0, stream>>>(W1, Wi1, 128, 2, 2, 65536);
  repack_w_kernel<<<256, 256, 0, stream>>>(W2, Wi2, 128, 2, 2, 65536);

  cin_mfma_layer<32,  1, 1, true,  true ><<<512, 512, 0, stream>>>(Wi0, x, nullptr, b0, hT1, outs, 0);
  cin_mfma_layer<128, 2, 2, false, true ><<<512, 512, 0, stream>>>(Wi1, x, hT1,    b1, hT2, outs, 128);
  cin_mfma_layer<128, 2, 2, false, false><<<512, 512, 0, stream>>>(Wi2, x, hT2,    b2, nullptr, outs, 256);

  cin_final_kernel<<<512, 64, 0, stream>>>(outs, Wout, bout, out);
}